// Round 28
// baseline (165.542 us; speedup 1.0000x reference)
//
#include <hip/hip_runtime.h>
#include <stdint.h>

#define NPTS 8192
#define NPAIR 4096
#define NB 4
#define KNN 16
#define RQ 2          // queries (rows) per wave
#define CCAP 24       // per-lane private column capacity (u16 PAIR indices)
#define DCAP 256      // dense staging for final select (pair entries)
#define MARGIN 1.5e-3f  // >> bound on |pk-approx - (exact d2 - qw)| (~2e-5)

typedef unsigned long long u64;
typedef unsigned int u32;
typedef unsigned short u16;
typedef float f32x2 __attribute__((ext_vector_type(2)));

__device__ __forceinline__ u32 f2ord(float f) {
    u32 b = __float_as_uint(f);
    return (b & 0x80000000u) ? ~b : (b | 0x80000000u);
}
__device__ __forceinline__ float ord2f(u32 u) {
    u32 b = (u & 0x80000000u) ? (u & 0x7fffffffu) : ~u;
    return __uint_as_float(b);
}
__device__ __forceinline__ u64 shflx64(u64 v, int m) {
    u32 lo = (u32)v, hi = (u32)(v >> 32);
    lo = __shfl_xor(lo, m, 64);
    hi = __shfl_xor(hi, m, 64);
    return ((u64)hi << 32) | lo;
}

// Pair-packed SoA: pos8[(b*NPAIR+m)*2+0] = {x0,x1,y0,y1}, +1 = {z0,z1,sq0,sq1}.
// sq via mul-add chain (np.sum(p*p)): ((x*x + y*y) + z*z), all _rn.
__global__ __launch_bounds__(256) void pack_kernel(const float* __restrict__ pos,
                                                   float4* __restrict__ pos8) {
    int t = blockIdx.x * 256 + threadIdx.x;   // 0..16383
    int b = t >> 12;
    int m = t & (NPAIR - 1);
    const float* p = pos + (size_t)b * 3 * NPTS;
    float2 x = *(const float2*)&p[2 * m];
    float2 y = *(const float2*)&p[NPTS + 2 * m];
    float2 z = *(const float2*)&p[2 * NPTS + 2 * m];
    float s0 = __fadd_rn(__fadd_rn(__fmul_rn(x.x, x.x), __fmul_rn(y.x, y.x)), __fmul_rn(z.x, z.x));
    float s1 = __fadd_rn(__fadd_rn(__fmul_rn(x.y, x.y), __fmul_rn(y.y, y.y)), __fmul_rn(z.y, z.y));
    pos8[2 * t]     = make_float4(x.x, x.y, y.x, y.y);
    pos8[2 * t + 1] = make_float4(z.x, z.y, s0, s1);
}

// exact reference d2 for BOTH candidates of pair m (one shared load pair).
// Query coords from broadcast vectors (qxv[r].x etc.) — bit-identical math.
#define RECOMP2(r, m, d0, d1)                                                           \
    { float4 _a = P8[2 * (m)], _c = P8[2 * (m) + 1];                                    \
      float _dot0 = __fmaf_rn(qzv[r].x, _c.x, __fmaf_rn(qyv[r].x, _a.z, __fmul_rn(qxv[r].x, _a.x))); \
      float _dot1 = __fmaf_rn(qzv[r].x, _c.y, __fmaf_rn(qyv[r].x, _a.w, __fmul_rn(qxv[r].x, _a.y))); \
      d0 = __fsub_rn(__fadd_rn(qw[r], _c.z), __fmul_rn(2.0f, _dot0));                   \
      d1 = __fsub_rn(__fadd_rn(qw[r], _c.w), __fmul_rn(2.0f, _dot1)); }

// PAIR-granular branchless append: one u16 write (pair index) + one
// conditional increment per pair per query. Append iff min(val0,val1) < Tm.
// A pruned pair has BOTH halves approx >= Tm = V16+2M -> exact strictly
// greater than 16 distinct-lane witnesses (2M >> approx err, no ties).
#define PROC(Av, Cv, mm)                                                                \
    {                                                                                   \
        f32x2 x01 = {(Av).x, (Av).y}, y01 = {(Av).z, (Av).w};                           \
        f32x2 z01 = {(Cv).x, (Cv).y}, sq01 = {(Cv).z, (Cv).w};                          \
        _Pragma("unroll")                                                               \
        for (int r = 0; r < RQ; ++r) {                                                  \
            f32x2 dot01 = __builtin_elementwise_fma(                                    \
                qzv[r], z01, __builtin_elementwise_fma(qyv[r], y01, qxv[r] * x01));     \
            f32x2 val01 = __builtin_elementwise_fma(n2v, dot01, sq01);                  \
            col[wv][r][c[r]][lane] = (u16)(mm);                                         \
            c[r] += (fminf(val01.x, val01.y) < Tm[r]) ? 1 : 0;                          \
        }                                                                               \
    }

// One wave serves RQ=2 rows. Scan: pk-approx conservative filter into per-lane
// LDS pair-columns (branchless); exact RECOMP2 only at tighten/final.
// CCAP=24 lets the trigger check run every 2 GROUPS: post-tighten c <= 16
// (trim-to-16), <=4 pair-appends/group/query -> max write index 23 < 24.
// Invariant: >=16 buffer candidates have exact (d2-qw) <= Tm - MARGIN; every
// prune/discard leaves >=16 strictly-smaller (d2,idx) keys. Final: exact keys.
__global__ __launch_bounds__(256) void knn_kernel(const float4* __restrict__ pos8,
                                                  float* __restrict__ out) {
    __shared__ u16 col[4][RQ][CCAP][64];
    __shared__ u16 dense[4][DCAP];
    const int lane = threadIdx.x & 63;
    const int wv = threadIdx.x >> 6;
    const int rowbase = blockIdx.x * (4 * RQ) + wv * RQ;   // 8 rows per block
    const int b = rowbase >> 13;
    const int ib = rowbase & (NPTS - 1);
    const float4* __restrict__ P8 = pos8 + (size_t)b * NPAIR * 2;
    const u64 below = (1ull << lane) - 1ull;

    f32x2 qxv[RQ], qyv[RQ], qzv[RQ];
    float qw[RQ];
    {
        int m = ib >> 1;   // ib even: both rows come from one pair
        float4 a = P8[2 * m], cc = P8[2 * m + 1];
        qxv[0] = (f32x2){a.x, a.x};  qyv[0] = (f32x2){a.z, a.z};
        qzv[0] = (f32x2){cc.x, cc.x}; qw[0] = cc.z;
        qxv[1] = (f32x2){a.y, a.y};  qyv[1] = (f32x2){a.w, a.w};
        qzv[1] = (f32x2){cc.y, cc.y}; qw[1] = cc.w;
    }
    const f32x2 n2v = {-2.0f, -2.0f};

    float Tm[RQ];   // filter threshold on approx val (= d2 - qw domain)
    int c[RQ];      // per-lane pair-column count

    // 16th-smallest of 64 per-lane f32 values via bitonic sort + broadcast
    auto rank16f = [&](float v) -> float {
#pragma unroll
        for (int k = 2; k <= 64; k <<= 1)
#pragma unroll
            for (int j = k >> 1; j >= 1; j >>= 1) {
                float o = __shfl_xor(v, j, 64);
                bool up = ((lane & k) == 0) == ((lane & j) == 0);
                v = (up ? (v < o) : (v > o)) ? v : o;
            }
        return __shfl(v, 15, 64);
    };

    // exact tighten: ordK = 16th lane-min of exact candidate ords; compact
    // pairs with min-ord <= ordK; per-lane trim to 16 pairs by pair-min-key.
    auto tighten = [&](int r) {
        u32 mn = 0xFFFFFFFFu;
#pragma unroll
        for (int t = 0; t < CCAP; ++t) {
            if (t < c[r]) {
                u32 m = (u32)col[wv][r][t][lane];
                float d0, d1; RECOMP2(r, m, d0, d1);
                u32 om = f2ord(d0); u32 o1 = f2ord(d1);
                om = o1 < om ? o1 : om;
                mn = om < mn ? om : mn;
            }
        }
        u32 v = mn;
#pragma unroll
        for (int k = 2; k <= 64; k <<= 1)
#pragma unroll
            for (int j = k >> 1; j >= 1; j >>= 1) {
                u32 o = (u32)__shfl_xor((int)v, j, 64);
                bool up = ((lane & k) == 0) == ((lane & j) == 0);
                v = (up ? (v < o) : (v > o)) ? v : o;
            }
        u32 ordK = (u32)__shfl((int)v, 15, 64);
        int nc = 0;
#pragma unroll
        for (int t = 0; t < CCAP; ++t) {
            if (t < c[r]) {
                u32 m = (u32)col[wv][r][t][lane];
                float d0, d1; RECOMP2(r, m, d0, d1);
                u32 om = f2ord(d0); u32 o1 = f2ord(d1);
                om = o1 < om ? o1 : om;
                if (om <= ordK) { col[wv][r][nc][lane] = (u16)m; ++nc; }
            }
        }
        c[r] = nc;
        // trim lane to its 16 smallest pair-min-keys
#pragma unroll 1
        for (int it = 0; it < CCAP - 16; ++it) {
            if (c[r] > 16) {
                u64 mx = 0; int mt = 0;
#pragma unroll
                for (int t = 0; t < CCAP; ++t) {
                    if (t < c[r]) {
                        u32 m = (u32)col[wv][r][t][lane];
                        float d0, d1; RECOMP2(r, m, d0, d1);
                        u32 o0 = f2ord(d0), o1 = f2ord(d1);
                        u64 key = (o1 < o0)
                            ? (((u64)o1 << 13) | (2 * m + 1))
                            : (((u64)o0 << 13) | (2 * m));
                        if (key > mx) { mx = key; mt = t; }
                    }
                }
                col[wv][r][mt][lane] = col[wv][r][c[r] - 1][lane];
                c[r] -= 1;
            }
        }
        Tm[r] = fminf(Tm[r], (ord2f(ordK) - qw[r]) + MARGIN);  // monotone
    };

    // ---- bootstrap: pairs 0..255 (512 cands) fully in registers ----
    {
        float4 A[4], C[4];
#pragma unroll
        for (int s = 0; s < 4; ++s) {
            int m = s * 64 + lane;
            A[s] = P8[2 * m];
            C[s] = P8[2 * m + 1];
        }
#pragma unroll
        for (int r = 0; r < RQ; ++r) {
            f32x2 vv[4];
            float mn = __uint_as_float(0x7f800000u);   // +inf
#pragma unroll
            for (int s = 0; s < 4; ++s) {
                f32x2 x01 = {A[s].x, A[s].y}, y01 = {A[s].z, A[s].w};
                f32x2 z01 = {C[s].x, C[s].y}, sq01 = {C[s].z, C[s].w};
                vv[s] = __builtin_elementwise_fma(
                    n2v, __builtin_elementwise_fma(qzv[r], z01,
                         __builtin_elementwise_fma(qyv[r], y01, qxv[r] * x01)), sq01);
                mn = fminf(mn, fminf(vv[s].x, vv[s].y));
            }
            float V16 = rank16f(mn);
            Tm[r] = V16 + 2.0f * MARGIN;
            c[r] = 0;
#pragma unroll
            for (int s = 0; s < 4; ++s) {
                int m = s * 64 + lane;
                col[wv][r][c[r]][lane] = (u16)m;
                c[r] += (fminf(vv[s].x, vv[s].y) < Tm[r]) ? 1 : 0;
            }
        }
    }

    // ---- steady scan: g = 1..15; trigger check every 2 groups ----
#pragma unroll 1
    for (int g = 1; g < 16; ++g) {
        if (g & 1) {   // checks at g = 1,3,5,...,15: gap of 2 groups max
            if (__ballot(c[0] > 16)) tighten(0);
            if (__ballot(c[1] > 16)) tighten(1);
        }
        int base = g * 256;
        float4 A[4], C[4];
#pragma unroll
        for (int s = 0; s < 4; ++s) {
            int m = base + s * 64 + lane;
            A[s] = P8[2 * m];
            C[s] = P8[2 * m + 1];
        }
        PROC(A[0], C[0], base + lane);
        PROC(A[1], C[1], base + 64 + lane);
        PROC(A[2], C[2], base + 128 + lane);
        PROC(A[3], C[3], base + 192 + lane);
    }

    // ---- final per query (sequential in r -> dense reuse is safe) ----
#pragma unroll
    for (int r = 0; r < RQ; ++r) {
        int sum = c[r];
#pragma unroll
        for (int s2 = 1; s2 < 64; s2 <<= 1) sum += __shfl_xor(sum, s2, 64);
        if (sum > 32) tighten(r);   // compacts to ~16-30 pairs -> fast path
        // gather pair entries into dense staging
        int nc = 0;
#pragma unroll 1
        for (int t = 0; t < CCAP; ++t) {
            bool valid = t < c[r];
            u64 bal = __ballot(valid);
            if (!bal) break;
            if (valid) dense[wv][nc + (int)__popcll(bal & below)] = col[wv][r][t][lane];
            nc += (int)__popcll(bal);
        }
        u64 myk = ~0ULL;
        if (nc <= 32) {
            // expand: lane i -> pair dense[i>>1], half i&1; sort-64 exact keys
            bool valid = lane < 2 * nc;
            u32 m = valid ? (u32)dense[wv][lane >> 1] : 0u;
            float d0, d1; RECOMP2(r, m, d0, d1);
            float dd = (lane & 1) ? d1 : d0;
            u64 v = valid ? (((u64)f2ord(dd) << 13) | (2 * m + (lane & 1))) : ~0ULL;
#pragma unroll
            for (int k = 2; k <= 64; k <<= 1)
#pragma unroll
                for (int j = k >> 1; j >= 1; j >>= 1) {
                    u64 o = shflx64(v, j);
                    bool up = ((lane & k) == 0) == ((lane & j) == 0);
                    v = (up ? (v < o) : (v > o)) ? v : o;
                }
            myk = v;   // lane holds rank = lane
        } else {
            // rare path: exact extract-min over <= 256 pairs (512 candidates)
            u64 s8[8];
#pragma unroll
            for (int t = 0; t < 4; ++t) {
                int bi = t * 64 + lane;
                bool valid = bi < nc;
                u32 m = valid ? (u32)dense[wv][bi] : 0u;
                float d0, d1; RECOMP2(r, m, d0, d1);
                s8[2 * t]     = valid ? (((u64)f2ord(d0) << 13) | (2 * m))     : ~0ULL;
                s8[2 * t + 1] = valid ? (((u64)f2ord(d1) << 13) | (2 * m + 1)) : ~0ULL;
            }
#pragma unroll 1
            for (int rr = 0; rr < KNN; ++rr) {
                u64 lm = s8[0];
#pragma unroll
                for (int t = 1; t < 8; ++t) lm = s8[t] < lm ? s8[t] : lm;
                u64 mm = lm;
#pragma unroll
                for (int s2 = 1; s2 < 64; s2 <<= 1) { u64 o = shflx64(mm, s2); mm = o < mm ? o : mm; }
#pragma unroll
                for (int t = 0; t < 8; ++t) s8[t] = (s8[t] == mm) ? ~0ULL : s8[t];
                if (lane == rr) myk = mm;
            }
        }
        if (lane < KNN) {
            int iq = ib + r;
            size_t o1 = (size_t)(b * KNN + lane) * NPTS + iq;
            out[o1] = (float)(u32)(myk & (u64)(NPTS - 1));
            out[(size_t)NB * KNN * NPTS + o1] = ord2f((u32)(myk >> 13));
        }
    }
}

extern "C" void kernel_launch(void* const* d_in, const int* in_sizes, int n_in,
                              void* d_out, int out_size, void* d_ws, size_t ws_size,
                              hipStream_t stream) {
    const float* pos = (const float*)d_in[0];
    float* out = (float*)d_out;
    float4* pos8 = (float4*)d_ws;   // 4*4096*2*16 B = 512 KB scratch

    pack_kernel<<<dim3(NB * NPAIR / 256), dim3(256), 0, stream>>>(pos, pos8);
    knn_kernel<<<dim3(NB * NPTS / 8), dim3(256), 0, stream>>>(pos8, out);
}

// Round 29
// 163.808 us; speedup vs baseline: 1.0106x; 1.0106x over previous
//
#include <hip/hip_runtime.h>
#include <stdint.h>

#define NPTS 8192
#define NPAIR 4096
#define NB 4
#define KNN 16
#define RQ 2          // queries (rows) per wave
#define CCAP 20       // per-lane private column capacity (u16 PAIR indices)
#define DCAP 256      // dense staging for final select (pair entries)
#define MARGIN 1.5e-3f  // >> bound on |pk-approx - (exact d2 - qw)| (~2e-5)

typedef unsigned long long u64;
typedef unsigned int u32;
typedef unsigned short u16;
typedef float f32x2 __attribute__((ext_vector_type(2)));

__device__ __forceinline__ u32 f2ord(float f) {
    u32 b = __float_as_uint(f);
    return (b & 0x80000000u) ? ~b : (b | 0x80000000u);
}
__device__ __forceinline__ float ord2f(u32 u) {
    u32 b = (u & 0x80000000u) ? (u & 0x7fffffffu) : ~u;
    return __uint_as_float(b);
}
__device__ __forceinline__ u64 shflx64(u64 v, int m) {
    u32 lo = (u32)v, hi = (u32)(v >> 32);
    lo = __shfl_xor(lo, m, 64);
    hi = __shfl_xor(hi, m, 64);
    return ((u64)hi << 32) | lo;
}

// Pair-packed SoA: pos8[(b*NPAIR+m)*2+0] = {x0,x1,y0,y1}, +1 = {z0,z1,sq0,sq1}.
// sq via mul-add chain (np.sum(p*p)): ((x*x + y*y) + z*z), all _rn.
__global__ __launch_bounds__(256) void pack_kernel(const float* __restrict__ pos,
                                                   float4* __restrict__ pos8) {
    int t = blockIdx.x * 256 + threadIdx.x;   // 0..16383
    int b = t >> 12;
    int m = t & (NPAIR - 1);
    const float* p = pos + (size_t)b * 3 * NPTS;
    float2 x = *(const float2*)&p[2 * m];
    float2 y = *(const float2*)&p[NPTS + 2 * m];
    float2 z = *(const float2*)&p[2 * NPTS + 2 * m];
    float s0 = __fadd_rn(__fadd_rn(__fmul_rn(x.x, x.x), __fmul_rn(y.x, y.x)), __fmul_rn(z.x, z.x));
    float s1 = __fadd_rn(__fadd_rn(__fmul_rn(x.y, x.y), __fmul_rn(y.y, y.y)), __fmul_rn(z.y, z.y));
    pos8[2 * t]     = make_float4(x.x, x.y, y.x, y.y);
    pos8[2 * t + 1] = make_float4(z.x, z.y, s0, s1);
}

// exact reference d2 for BOTH candidates of pair m (one shared load pair).
// Query coords from broadcast vectors (qxv[r].x etc.) — bit-identical math.
#define RECOMP2(r, m, d0, d1)                                                           \
    { float4 _a = P8[2 * (m)], _c = P8[2 * (m) + 1];                                    \
      float _dot0 = __fmaf_rn(qzv[r].x, _c.x, __fmaf_rn(qyv[r].x, _a.z, __fmul_rn(qxv[r].x, _a.x))); \
      float _dot1 = __fmaf_rn(qzv[r].x, _c.y, __fmaf_rn(qyv[r].x, _a.w, __fmul_rn(qxv[r].x, _a.y))); \
      d0 = __fsub_rn(__fadd_rn(qw[r], _c.z), __fmul_rn(2.0f, _dot0));                   \
      d1 = __fsub_rn(__fadd_rn(qw[r], _c.w), __fmul_rn(2.0f, _dot1)); }

// PAIR-granular branchless append: one u16 write (pair index) + one
// conditional increment per pair per query. Append iff min(val0,val1) < Tm.
// A pruned pair has BOTH halves approx >= Tm = V16+2M -> exact strictly
// greater than 16 distinct-lane witnesses (2M >> approx err, no ties).
#define PROC(Av, Cv, mm)                                                                \
    {                                                                                   \
        f32x2 x01 = {(Av).x, (Av).y}, y01 = {(Av).z, (Av).w};                           \
        f32x2 z01 = {(Cv).x, (Cv).y}, sq01 = {(Cv).z, (Cv).w};                          \
        _Pragma("unroll")                                                               \
        for (int r = 0; r < RQ; ++r) {                                                  \
            f32x2 dot01 = __builtin_elementwise_fma(                                    \
                qzv[r], z01, __builtin_elementwise_fma(qyv[r], y01, qxv[r] * x01));     \
            f32x2 val01 = __builtin_elementwise_fma(n2v, dot01, sq01);                  \
            col[wv][r][c[r]][lane] = (u16)(mm);                                         \
            c[r] += (fminf(val01.x, val01.y) < Tm[r]) ? 1 : 0;                          \
        }                                                                               \
    }

// One wave serves RQ=2 rows. Scan: pk-approx conservative filter into per-lane
// LDS pair-columns (branchless); exact RECOMP2 only at tighten/final.
// Pair granularity bounds appends to 4/group/query, so ONE trigger check per
// group suffices: post-tighten c <= 16, +4 -> max write index 19 < CCAP = 20.
// Invariant: >=16 buffer candidates have exact (d2-qw) <= Tm - MARGIN; every
// prune/discard leaves >=16 strictly-smaller (d2,idx) keys. Final: exact keys.
__global__ __launch_bounds__(256) void knn_kernel(const float4* __restrict__ pos8,
                                                  float* __restrict__ out) {
    __shared__ u16 col[4][RQ][CCAP][64];
    __shared__ u16 dense[4][DCAP];
    const int lane = threadIdx.x & 63;
    const int wv = threadIdx.x >> 6;
    const int rowbase = blockIdx.x * (4 * RQ) + wv * RQ;   // 8 rows per block
    const int b = rowbase >> 13;
    const int ib = rowbase & (NPTS - 1);
    const float4* __restrict__ P8 = pos8 + (size_t)b * NPAIR * 2;
    const u64 below = (1ull << lane) - 1ull;

    f32x2 qxv[RQ], qyv[RQ], qzv[RQ];
    float qw[RQ];
    {
        int m = ib >> 1;   // ib even: both rows come from one pair
        float4 a = P8[2 * m], cc = P8[2 * m + 1];
        qxv[0] = (f32x2){a.x, a.x};  qyv[0] = (f32x2){a.z, a.z};
        qzv[0] = (f32x2){cc.x, cc.x}; qw[0] = cc.z;
        qxv[1] = (f32x2){a.y, a.y};  qyv[1] = (f32x2){a.w, a.w};
        qzv[1] = (f32x2){cc.y, cc.y}; qw[1] = cc.w;
    }
    const f32x2 n2v = {-2.0f, -2.0f};

    float Tm[RQ];   // filter threshold on approx val (= d2 - qw domain)
    int c[RQ];      // per-lane pair-column count

    // 16th-smallest of 64 per-lane f32 values via bitonic sort + broadcast
    auto rank16f = [&](float v) -> float {
#pragma unroll
        for (int k = 2; k <= 64; k <<= 1)
#pragma unroll
            for (int j = k >> 1; j >= 1; j >>= 1) {
                float o = __shfl_xor(v, j, 64);
                bool up = ((lane & k) == 0) == ((lane & j) == 0);
                v = (up ? (v < o) : (v > o)) ? v : o;
            }
        return __shfl(v, 15, 64);
    };

    // exact tighten: ordK = 16th lane-min of exact candidate ords; compact
    // pairs with min-ord <= ordK; per-lane trim to 16 pairs by pair-min-key.
    auto tighten = [&](int r) {
        u32 mn = 0xFFFFFFFFu;
#pragma unroll
        for (int t = 0; t < CCAP; ++t) {
            if (t < c[r]) {
                u32 m = (u32)col[wv][r][t][lane];
                float d0, d1; RECOMP2(r, m, d0, d1);
                u32 om = f2ord(d0); u32 o1 = f2ord(d1);
                om = o1 < om ? o1 : om;
                mn = om < mn ? om : mn;
            }
        }
        u32 v = mn;
#pragma unroll
        for (int k = 2; k <= 64; k <<= 1)
#pragma unroll
            for (int j = k >> 1; j >= 1; j >>= 1) {
                u32 o = (u32)__shfl_xor((int)v, j, 64);
                bool up = ((lane & k) == 0) == ((lane & j) == 0);
                v = (up ? (v < o) : (v > o)) ? v : o;
            }
        u32 ordK = (u32)__shfl((int)v, 15, 64);
        int nc = 0;
#pragma unroll
        for (int t = 0; t < CCAP; ++t) {
            if (t < c[r]) {
                u32 m = (u32)col[wv][r][t][lane];
                float d0, d1; RECOMP2(r, m, d0, d1);
                u32 om = f2ord(d0); u32 o1 = f2ord(d1);
                om = o1 < om ? o1 : om;
                if (om <= ordK) { col[wv][r][nc][lane] = (u16)m; ++nc; }
            }
        }
        c[r] = nc;
        // trim lane to its 16 smallest pair-min-keys
#pragma unroll 1
        for (int it = 0; it < CCAP - 16; ++it) {
            if (c[r] > 16) {
                u64 mx = 0; int mt = 0;
#pragma unroll
                for (int t = 0; t < CCAP; ++t) {
                    if (t < c[r]) {
                        u32 m = (u32)col[wv][r][t][lane];
                        float d0, d1; RECOMP2(r, m, d0, d1);
                        u32 o0 = f2ord(d0), o1 = f2ord(d1);
                        u64 key = (o1 < o0)
                            ? (((u64)o1 << 13) | (2 * m + 1))
                            : (((u64)o0 << 13) | (2 * m));
                        if (key > mx) { mx = key; mt = t; }
                    }
                }
                col[wv][r][mt][lane] = col[wv][r][c[r] - 1][lane];
                c[r] -= 1;
            }
        }
        Tm[r] = fminf(Tm[r], (ord2f(ordK) - qw[r]) + MARGIN);  // monotone
    };

    // ---- bootstrap: pairs 0..255 (512 cands) fully in registers ----
    {
        float4 A[4], C[4];
#pragma unroll
        for (int s = 0; s < 4; ++s) {
            int m = s * 64 + lane;
            A[s] = P8[2 * m];
            C[s] = P8[2 * m + 1];
        }
#pragma unroll
        for (int r = 0; r < RQ; ++r) {
            f32x2 vv[4];
            float mn = __uint_as_float(0x7f800000u);   // +inf
#pragma unroll
            for (int s = 0; s < 4; ++s) {
                f32x2 x01 = {A[s].x, A[s].y}, y01 = {A[s].z, A[s].w};
                f32x2 z01 = {C[s].x, C[s].y}, sq01 = {C[s].z, C[s].w};
                vv[s] = __builtin_elementwise_fma(
                    n2v, __builtin_elementwise_fma(qzv[r], z01,
                         __builtin_elementwise_fma(qyv[r], y01, qxv[r] * x01)), sq01);
                mn = fminf(mn, fminf(vv[s].x, vv[s].y));
            }
            float V16 = rank16f(mn);
            Tm[r] = V16 + 2.0f * MARGIN;
            c[r] = 0;
#pragma unroll
            for (int s = 0; s < 4; ++s) {
                int m = s * 64 + lane;
                col[wv][r][c[r]][lane] = (u16)m;
                c[r] += (fminf(vv[s].x, vv[s].y) < Tm[r]) ? 1 : 0;
            }
        }
    }

    // ---- steady scan: g = 1..15, 4 pair-slots; ONE trigger check per group ----
#pragma unroll 1
    for (int g = 1; g < 16; ++g) {
        if (__ballot(c[0] > 16)) tighten(0);   // post: c <= 16; +4 max per group
        if (__ballot(c[1] > 16)) tighten(1);
        int base = g * 256;
        float4 A[4], C[4];
#pragma unroll
        for (int s = 0; s < 4; ++s) {
            int m = base + s * 64 + lane;
            A[s] = P8[2 * m];
            C[s] = P8[2 * m + 1];
        }
        PROC(A[0], C[0], base + lane);
        PROC(A[1], C[1], base + 64 + lane);
        PROC(A[2], C[2], base + 128 + lane);
        PROC(A[3], C[3], base + 192 + lane);
    }

    // ---- final per query (sequential in r -> dense reuse is safe) ----
#pragma unroll
    for (int r = 0; r < RQ; ++r) {
        int sum = c[r];
#pragma unroll
        for (int s2 = 1; s2 < 64; s2 <<= 1) sum += __shfl_xor(sum, s2, 64);
        if (sum > 32) tighten(r);   // compacts to ~16-30 pairs -> fast path
        // gather pair entries into dense staging
        int nc = 0;
#pragma unroll 1
        for (int t = 0; t < CCAP; ++t) {
            bool valid = t < c[r];
            u64 bal = __ballot(valid);
            if (!bal) break;
            if (valid) dense[wv][nc + (int)__popcll(bal & below)] = col[wv][r][t][lane];
            nc += (int)__popcll(bal);
        }
        u64 myk = ~0ULL;
        if (nc <= 32) {
            // expand: lane i -> pair dense[i>>1], half i&1; sort-64 exact keys
            bool valid = lane < 2 * nc;
            u32 m = valid ? (u32)dense[wv][lane >> 1] : 0u;
            float d0, d1; RECOMP2(r, m, d0, d1);
            float dd = (lane & 1) ? d1 : d0;
            u64 v = valid ? (((u64)f2ord(dd) << 13) | (2 * m + (lane & 1))) : ~0ULL;
#pragma unroll
            for (int k = 2; k <= 64; k <<= 1)
#pragma unroll
                for (int j = k >> 1; j >= 1; j >>= 1) {
                    u64 o = shflx64(v, j);
                    bool up = ((lane & k) == 0) == ((lane & j) == 0);
                    v = (up ? (v < o) : (v > o)) ? v : o;
                }
            myk = v;   // lane holds rank = lane
        } else {
            // rare path: exact extract-min over <= 256 pairs (512 candidates)
            u64 s8[8];
#pragma unroll
            for (int t = 0; t < 4; ++t) {
                int bi = t * 64 + lane;
                bool valid = bi < nc;
                u32 m = valid ? (u32)dense[wv][bi] : 0u;
                float d0, d1; RECOMP2(r, m, d0, d1);
                s8[2 * t]     = valid ? (((u64)f2ord(d0) << 13) | (2 * m))     : ~0ULL;
                s8[2 * t + 1] = valid ? (((u64)f2ord(d1) << 13) | (2 * m + 1)) : ~0ULL;
            }
#pragma unroll 1
            for (int rr = 0; rr < KNN; ++rr) {
                u64 lm = s8[0];
#pragma unroll
                for (int t = 1; t < 8; ++t) lm = s8[t] < lm ? s8[t] : lm;
                u64 mm = lm;
#pragma unroll
                for (int s2 = 1; s2 < 64; s2 <<= 1) { u64 o = shflx64(mm, s2); mm = o < mm ? o : mm; }
#pragma unroll
                for (int t = 0; t < 8; ++t) s8[t] = (s8[t] == mm) ? ~0ULL : s8[t];
                if (lane == rr) myk = mm;
            }
        }
        if (lane < KNN) {
            int iq = ib + r;
            size_t o1 = (size_t)(b * KNN + lane) * NPTS + iq;
            out[o1] = (float)(u32)(myk & (u64)(NPTS - 1));
            out[(size_t)NB * KNN * NPTS + o1] = ord2f((u32)(myk >> 13));
        }
    }
}

extern "C" void kernel_launch(void* const* d_in, const int* in_sizes, int n_in,
                              void* d_out, int out_size, void* d_ws, size_t ws_size,
                              hipStream_t stream) {
    const float* pos = (const float*)d_in[0];
    float* out = (float*)d_out;
    float4* pos8 = (float4*)d_ws;   // 4*4096*2*16 B = 512 KB scratch

    pack_kernel<<<dim3(NB * NPAIR / 256), dim3(256), 0, stream>>>(pos, pos8);
    knn_kernel<<<dim3(NB * NPTS / 8), dim3(256), 0, stream>>>(pos8, out);
}